// Round 3
// baseline (458.047 us; speedup 1.0000x reference)
//
#include <hip/hip_runtime.h>

// EGNN fused layer, MI355X gfx950 — v4 (atomic-reduction round).
// out[0 : 50000*64)          = h + segment_sum(node messages, dst)
// out[50000*64 : +50000*3)   = x + segment_sum(coord updates, dst)
//
// v3 post-mortem: dur pinned at 340-360us across 3 rounds with wildly
// different VALU/occupancy/barrier structure; WRITE_SIZE byte-identical;
// all pipes <40%.  Invariant = 53.6M f32 atomicAdds (158 G/s device rate)
// -> theory: device-scope atomic RMW throughput at the coherence point is
// the floor; dur ~ f(atomic count).
// Changes vs v3:
//  - device-side counting sort of edges by dst (hist + 2-level scan +
//    scatter into workspace; ~1.6M extra atomics, recomputed every launch
//    so workspace re-poisoning is safe).  Avg run length = 16.
//  - outh: GEMM2 result -> LDS f32 tile, segmented column-reduction over
//    sorted dst runs; one coalesced 64-lane atomic burst per run-quarter.
//    4096 -> ~500 atomics/tile  (51.2M -> ~6.3M total).
//  - outx: per-edge contribution -> LDS, run-start lanes combine.
//    192 -> ~15 atomics/tile.
//  - fallback: if ws_size too small for sort buffers, main kernel runs on
//    unsorted inputs (runs of length 1 -> v3-equivalent per-edge atomics).

#define NN 50000
#define NE 800000
#define NDIM 64
#define HDIM 128
#define EDIM 32
#define NTILES (NE / 64)      // 12500, exact
#define MSTRIDE 168           // m_input LDS row stride (ushorts): 160 + 8 pad
#define HSTRIDE 136           // hidden LDS row stride: 128 + 8 pad
#define MLSTRIDE 65           // f32 m-tile stride (floats)
#define NH (NN * NDIM)        // 3,200,000
#define NX (NN * 3)           // 150,000

// workspace layout
#define WS_WN1P 0             // [160][128] floats
#define WS_WC1P 20480         // [160][128]
#define WS_BN1P 40960         // [128]
#define WS_BC1P 41088         // [128]
#define WS_WEIGHTS_FLOATS 65536   // weights region padded to 64K floats
#define NCNT 50176            // 196 * 256, counters padded
// int offsets from (int*)ws:
#define IOFF_CNT    WS_WEIGHTS_FLOATS
#define IOFF_BLK    (IOFF_CNT + NCNT)
#define IOFF_CUR    (IOFF_BLK + 256)
#define IOFF_SRCS   (IOFF_CUR + NCNT)
#define IOFF_DSTS   (IOFF_SRCS + NE)
#define IOFF_DISTS  (IOFF_DSTS + NE)
#define WS_TOTAL_BYTES ((size_t)(IOFF_DISTS + NE) * 4)

typedef __bf16 bf16x8 __attribute__((ext_vector_type(8)));
typedef float f32x4 __attribute__((ext_vector_type(4)));
typedef unsigned short ushort8 __attribute__((ext_vector_type(8)));
typedef unsigned short ushort4v __attribute__((ext_vector_type(4)));

__device__ __forceinline__ unsigned short f2bf(float f) {
    union { __bf16 b; unsigned short u; } c;
    c.b = (__bf16)f;            // HW v_cvt (RNE)
    return c.u;
}
__device__ __forceinline__ float silu(float v) {
    return __fdividef(v, 1.0f + __expf(-v));
}

// lgkm-only barrier: all cross-thread deps in the main kernel flow through
// LDS. Deliberately does NOT drain vmcnt -> atomics stay in flight.
__device__ __forceinline__ void bar_lds() {
    asm volatile("s_waitcnt lgkmcnt(0)" ::: "memory");
    __builtin_amdgcn_s_barrier();
}

__device__ __forceinline__ bf16x8 ld_frag(const unsigned short* p) {
    union { ushort8 u; bf16x8 v; } c;
    c.u = *(const ushort8*)p;
    return c.v;
}
__device__ __forceinline__ bf16x8 mk_frag(const unsigned short* u) {
    union { ushort8 uu; bf16x8 v; } c;
#pragma unroll
    for (int j = 0; j < 8; ++j) c.uu[j] = u[j];
    return c.v;
}

__global__ void init_out(const float* __restrict__ h, const float* __restrict__ x,
                         float* __restrict__ out) {
    int i = blockIdx.x * 256 + threadIdx.x;
    if (i < NH) out[i] = h[i];
    else if (i < NH + NX) out[i] = x[i - NH];
}

// ---------------- counting-sort pipeline (runs every launch) ----------------

__global__ __launch_bounds__(256) void zero_cnt(int* __restrict__ cnt, int* __restrict__ cur) {
    const int i = blockIdx.x * 256 + threadIdx.x;
    if (i < NCNT) { cnt[i] = 0; cur[i] = 0; }
}

__global__ __launch_bounds__(256) void hist_dst(const int* __restrict__ dst, int* __restrict__ cnt) {
    const int e = blockIdx.x * 256 + threadIdx.x;
    if (e < NE) atomicAdd(&cnt[dst[e]], 1);
}

// block-level exclusive scan of 256 counters; block sum -> blk[b]
__global__ __launch_bounds__(256) void scan1(int* __restrict__ cnt, int* __restrict__ blk) {
    __shared__ int sh[256];
    const int t = threadIdx.x, i = blockIdx.x * 256 + t;
    const int v = cnt[i];
    sh[t] = v;
    __syncthreads();
#pragma unroll
    for (int d = 1; d < 256; d <<= 1) {
        const int o = (t >= d) ? sh[t - d] : 0;
        __syncthreads();
        sh[t] += o;
        __syncthreads();
    }
    cnt[i] = sh[t] - v;                       // exclusive within block
    if (t == 255) blk[blockIdx.x] = sh[t];    // inclusive block total
}

// single-block exclusive scan of the 196 block sums
__global__ __launch_bounds__(256) void scan2(int* __restrict__ blk) {
    __shared__ int sh[256];
    const int t = threadIdx.x;
    const int v = (t < 196) ? blk[t] : 0;
    sh[t] = v;
    __syncthreads();
#pragma unroll
    for (int d = 1; d < 256; d <<= 1) {
        const int o = (t >= d) ? sh[t - d] : 0;
        __syncthreads();
        sh[t] += o;
        __syncthreads();
    }
    if (t < 196) blk[t] = sh[t] - v;          // exclusive
}

__global__ __launch_bounds__(256) void scan3(int* __restrict__ cnt, const int* __restrict__ blk) {
    const int i = blockIdx.x * 256 + threadIdx.x;
    if (i < NCNT) cnt[i] += blk[blockIdx.x];
}

__global__ __launch_bounds__(256) void scatter_edges(
    const int* __restrict__ src, const int* __restrict__ dst,
    const float* __restrict__ dist,
    const int* __restrict__ base, int* __restrict__ cur,
    int* __restrict__ srcs, int* __restrict__ dsts, float* __restrict__ dists) {
    const int e = blockIdx.x * 256 + threadIdx.x;
    if (e < NE) {
        const int d = dst[e];
        const int pos = base[d] + atomicAdd(&cur[d], 1);
        srcs[pos] = src[e];
        dsts[pos] = d;
        dists[pos] = dist[e];
    }
}

// ---------------- weight folding (unchanged from v3) ----------------

__global__ __launch_bounds__(128) void fold_weights(
    const float* __restrict__ We2, const float* __restrict__ be2,
    const float* __restrict__ Wn1, const float* __restrict__ bn1,
    const float* __restrict__ Wc1, const float* __restrict__ bc1,
    float* __restrict__ ws) {
    const int b = blockIdx.x;
    const int col = threadIdx.x;
    if (b < 320) {
        const int path = (b >= 160);
        const float* W = path ? Wc1 : Wn1;
        float* Wp = ws + (path ? WS_WC1P : WS_WN1P);
        const int r = path ? (b - 160) : b;
        if (r < 128) {
            Wp[r * 128 + col] = W[r * 128 + col];
        } else {
            const int j = r - 128;          // s-dim index 0..31
            float s = 0.0f;
#pragma unroll
            for (int n = 0; n < 32; ++n)
                s += We2[j * 32 + n] * W[(128 + n) * 128 + col];
            Wp[r * 128 + col] = s;
        }
    } else {
        const int path = b - 320;
        const float* W = path ? Wc1 : Wn1;
        const float* bb = path ? bc1 : bn1;
        float* bp = ws + (path ? WS_BC1P : WS_BN1P);
        float s = bb[col];
#pragma unroll
        for (int n = 0; n < 32; ++n)
            s += be2[n] * W[(128 + n) * 128 + col];
        bp[col] = s;
    }
}

// ---------------- main fused kernel ----------------

__global__ __launch_bounds__(256, 2) void egnn_edges(
    const float* __restrict__ h, const float* __restrict__ x,
    const int* __restrict__ srcg, const int* __restrict__ dstg,
    const float* __restrict__ dist,
    const float* __restrict__ We1, const float* __restrict__ be1,
    const float* __restrict__ Wn2, const float* __restrict__ bn2,
    const float* __restrict__ Wc2,
    const float* __restrict__ wsW,
    float* __restrict__ outh, float* __restrict__ outx) {

    __shared__ __align__(16) unsigned short mlds[64 * MSTRIDE];  // m_input bf16; f32 m-tile view later
    __shared__ __align__(16) unsigned short hl[64 * HSTRIDE];    // hidden tile bf16
    __shared__ int src_l[64];
    __shared__ int dst_l[64];
    __shared__ float we1_l[32], be1_l[32];
    __shared__ float part_l[256];
    __shared__ float cx_l[64], cy_l[64], cz_l[64];

    const int tid  = threadIdx.x;
    const int w    = tid >> 6;        // wave 0..3
    const int lane = tid & 63;
    const int l15  = lane & 15;
    const int quad = lane >> 4;

    const float* Wn1p = wsW + WS_WN1P;
    const float* Wc1p = wsW + WS_WC1P;
    const float* bn1p = wsW + WS_BN1P;
    const float* bc1p = wsW + WS_BC1P;

    if (tid < 32) { we1_l[tid] = We1[tid]; be1_l[tid] = be1[tid]; }

    // ---- one-time: B-fragments to registers (from folded weights) ----
    bf16x8 wn1f[5][2], wc1f[5][2];
#pragma unroll
    for (int kc = 0; kc < 5; ++kc) {
#pragma unroll
        for (int nt = 0; nt < 2; ++nt) {
            unsigned short un[8], uc[8];
            const int n = w * 32 + nt * 16 + l15;
#pragma unroll
            for (int j = 0; j < 8; ++j) {
                const int k = kc * 32 + quad * 8 + j;
                un[j] = f2bf(Wn1p[k * HDIM + n]);
                uc[j] = f2bf(Wc1p[k * HDIM + n]);
            }
            wn1f[kc][nt] = mk_frag(un);
            wc1f[kc][nt] = mk_frag(uc);
        }
    }
    bf16x8 wn2f[4];
#pragma unroll
    for (int kc = 0; kc < 4; ++kc) {
        unsigned short u[8];
        const int n = w * 16 + l15;
#pragma unroll
        for (int j = 0; j < 8; ++j) {
            const int k = kc * 32 + quad * 8 + j;
            u[j] = f2bf(Wn2[k * NDIM + n]);
        }
        wn2f[kc] = mk_frag(u);
    }
    const float biasN0 = bn1p[w * 32 + l15];
    const float biasN1 = bn1p[w * 32 + 16 + l15];
    const float biasC0 = bc1p[w * 32 + l15];
    const float biasC1 = bc1p[w * 32 + 16 + l15];
    const float bias2v = bn2[w * 16 + l15];
    const float wcA = Wc2[w * 32 + l15];          // coord Wc2 slice, nt=0
    const float wcB = Wc2[w * 32 + 16 + l15];     // nt=1

    for (int tile = blockIdx.x; tile < NTILES; tile += gridDim.x) {
        // prefetch src/dst into regs while previous tile's epilogue finishes
        int pf_s = 0, pf_d = 0;
        if (tid < 64) {
            const int e = tile * 64 + tid;
            pf_s = srcg[e];
            pf_d = dstg[e];
        }
        bar_lds();   // (1) protect LDS reuse from previous iteration

        if (tid < 64) { src_l[tid] = pf_s; dst_l[tid] = pf_d; }
        bar_lds();   // (2)

        // ---- stage m_input = [h[src] | h[dst] | s] as bf16 ----
        {
            const int c4 = tid & 15, sub = tid >> 4;
#pragma unroll
            for (int it = 0; it < 4; ++it) {
                const int el = sub + it * 16;
                const float4 hs = *(const float4*)(h + (size_t)src_l[el] * NDIM + c4 * 4);
                const float4 hd = *(const float4*)(h + (size_t)dst_l[el] * NDIM + c4 * 4);
                ushort4v us = { f2bf(hs.x), f2bf(hs.y), f2bf(hs.z), f2bf(hs.w) };
                ushort4v ud = { f2bf(hd.x), f2bf(hd.y), f2bf(hd.z), f2bf(hd.w) };
                *(ushort4v*)&mlds[el * MSTRIDE + c4 * 4] = us;
                *(ushort4v*)&mlds[el * MSTRIDE + 64 + c4 * 4] = ud;
            }
        }
        // ---- stage s = silu(d*We1 + be1)  (8 values/thread) ----
        {
            const int el = tid >> 2, j0 = (tid & 3) * 8;
            const float dv = dist[tile * 64 + el];
            ushort8 u;
#pragma unroll
            for (int j = 0; j < 8; ++j)
                u[j] = f2bf(silu(dv * we1_l[j0 + j] + be1_l[j0 + j]));
            *(ushort8*)&mlds[el * MSTRIDE + 128 + j0] = u;
        }
        bar_lds();   // (3)

        // ---- GEMM1: [64x160] @ {Wn1', Wc1'} -> hidden [64x128] per path ----
        f32x4 accN[4][2], accC[4][2];
#pragma unroll
        for (int mt = 0; mt < 4; ++mt) {
            accN[mt][0] = (f32x4){biasN0, biasN0, biasN0, biasN0};
            accN[mt][1] = (f32x4){biasN1, biasN1, biasN1, biasN1};
            accC[mt][0] = (f32x4){biasC0, biasC0, biasC0, biasC0};
            accC[mt][1] = (f32x4){biasC1, biasC1, biasC1, biasC1};
        }
#pragma unroll
        for (int kc = 0; kc < 5; ++kc) {
            bf16x8 af[4];
#pragma unroll
            for (int mt = 0; mt < 4; ++mt)
                af[mt] = ld_frag(&mlds[(mt * 16 + l15) * MSTRIDE + kc * 32 + quad * 8]);
#pragma unroll
            for (int mt = 0; mt < 4; ++mt) {
#pragma unroll
                for (int nt = 0; nt < 2; ++nt) {
                    accN[mt][nt] = __builtin_amdgcn_mfma_f32_16x16x32_bf16(
                        af[mt], wn1f[kc][nt], accN[mt][nt], 0, 0, 0);
                    accC[mt][nt] = __builtin_amdgcn_mfma_f32_16x16x32_bf16(
                        af[mt], wc1f[kc][nt], accC[mt][nt], 0, 0, 0);
                }
            }
        }

        // ---- node path: silu -> hl (C-layout -> A-layout round trip) ----
#pragma unroll
        for (int mt = 0; mt < 4; ++mt)
#pragma unroll
            for (int nt = 0; nt < 2; ++nt)
#pragma unroll
                for (int r = 0; r < 4; ++r)
                    hl[(mt * 16 + quad * 4 + r) * HSTRIDE + w * 32 + nt * 16 + l15] =
                        f2bf(silu(accN[mt][nt][r]));

        // ---- coord path: in-register silu*Wc2 + butterfly reduce over l15 ----
        {
            float p[16];
#pragma unroll
            for (int mt = 0; mt < 4; ++mt)
#pragma unroll
                for (int r = 0; r < 4; ++r)
                    p[mt * 4 + r] = silu(accC[mt][0][r]) * wcA + silu(accC[mt][1][r]) * wcB;

            float q8[8];
#pragma unroll
            for (int i = 0; i < 8; ++i) {
                const float send = (l15 & 8) ? p[i] : p[i + 8];
                const float recv = __shfl_xor(send, 8, 64);
                q8[i] = ((l15 & 8) ? p[i + 8] : p[i]) + recv;
            }
            float q4[4];
#pragma unroll
            for (int i = 0; i < 4; ++i) {
                const float send = (l15 & 4) ? q8[i] : q8[i + 4];
                const float recv = __shfl_xor(send, 4, 64);
                q4[i] = ((l15 & 4) ? q8[i + 4] : q8[i]) + recv;
            }
            float q2[2];
#pragma unroll
            for (int i = 0; i < 2; ++i) {
                const float send = (l15 & 2) ? q4[i] : q4[i + 2];
                const float recv = __shfl_xor(send, 2, 64);
                q2[i] = ((l15 & 2) ? q4[i + 2] : q4[i]) + recv;
            }
            {
                const float send = (l15 & 1) ? q2[0] : q2[1];
                const float recv = __shfl_xor(send, 1, 64);
                const float tot = ((l15 & 1) ? q2[1] : q2[0]) + recv;
                const int edge = (l15 >> 2) * 16 + quad * 4 + (l15 & 3);
                part_l[w * 64 + edge] = tot;
            }
        }
        bar_lds();   // (4) hl ready for GEMM2, part_l ready for epilogue

        // ---- GEMM2 node: [64x128] @ Wn2 -> m [64x64] ----
        f32x4 acc2[4];
#pragma unroll
        for (int mt = 0; mt < 4; ++mt) acc2[mt] = (f32x4){bias2v, bias2v, bias2v, bias2v};
#pragma unroll
        for (int kc = 0; kc < 4; ++kc) {
#pragma unroll
            for (int mt = 0; mt < 4; ++mt) {
                bf16x8 a2 = ld_frag(&hl[(mt * 16 + l15) * HSTRIDE + kc * 32 + quad * 8]);
                acc2[mt] = __builtin_amdgcn_mfma_f32_16x16x32_bf16(a2, wn2f[kc], acc2[mt], 0, 0, 0);
            }
        }

        // ---- m -> LDS f32 tile (reuse mlds; all mlds bf16 reads done pre-(4)) ----
        {
            float* ml = (float*)mlds;   // [64][MLSTRIDE] floats, 16.6 KB of 43 KB
#pragma unroll
            for (int mt = 0; mt < 4; ++mt)
#pragma unroll
                for (int r = 0; r < 4; ++r)
                    ml[(mt * 16 + quad * 4 + r) * MLSTRIDE + w * 16 + l15] = acc2[mt][r];
        }

        // ---- coord per-edge contributions -> LDS (consumed post-(5)) ----
        if (tid < 64) {
            const float cw = part_l[tid] + part_l[64 + tid] + part_l[128 + tid] + part_l[192 + tid];
            const int sn = src_l[tid], dn = dst_l[tid];
            const float dx = x[sn * 3 + 0] - x[dn * 3 + 0];
            const float dy = x[sn * 3 + 1] - x[dn * 3 + 1];
            const float dz = x[sn * 3 + 2] - x[dn * 3 + 2];
            float len = sqrtf(dx * dx + dy * dy + dz * dz);
            len = fmaxf(len, 1e-8f);
            const float f = cw / len;
            cx_l[tid] = f * dx; cy_l[tid] = f * dy; cz_l[tid] = f * dz;
        }
        bar_lds();   // (5) ml + cx/cy/cz ready

        // ---- segmented reduction over sorted-dst runs, coalesced atomics ----
        // wave g owns rows [16g, 16g+16), lane owns column c.  Branches are
        // wave-uniform (all lanes share the row's dst); each flush is a
        // 64-lane contiguous 256B atomic burst.
        {
            const int c = lane, g = w;
            const int r0 = g * 16;
            float acc = ((const float*)mlds)[r0 * MLSTRIDE + c];
            int d = dst_l[r0];
#pragma unroll
            for (int r = r0 + 1; r < r0 + 16; ++r) {
                const int dn = dst_l[r];
                if (dn != d) {
                    atomicAdd(outh + (size_t)d * NDIM + c, acc);
                    acc = 0.0f;
                    d = dn;
                }
                acc += ((const float*)mlds)[r * MLSTRIDE + c];
            }
            atomicAdd(outh + (size_t)d * NDIM + c, acc);
        }

        // ---- coord: run-start lanes combine their run, 3 atomics per run ----
        if (tid < 64) {
            const int d = dst_l[tid];
            if (tid == 0 || dst_l[tid - 1] != d) {
                float sx = 0.0f, sy = 0.0f, sz = 0.0f;
                int r = tid;
                do {
                    sx += cx_l[r]; sy += cy_l[r]; sz += cz_l[r];
                    ++r;
                } while (r < 64 && dst_l[r] == d);
                atomicAdd(outx + (size_t)d * 3 + 0, sx);
                atomicAdd(outx + (size_t)d * 3 + 1, sy);
                atomicAdd(outx + (size_t)d * 3 + 2, sz);
            }
        }
    }
}

extern "C" void kernel_launch(void* const* d_in, const int* in_sizes, int n_in,
                              void* d_out, int out_size, void* d_ws, size_t ws_size,
                              hipStream_t stream) {
    const float* h    = (const float*)d_in[0];
    const float* x    = (const float*)d_in[1];
    const int*   ei   = (const int*)d_in[2];     // int32, [2, NE]
    const float* dist = (const float*)d_in[3];
    const float* We1  = (const float*)d_in[4];
    const float* be1  = (const float*)d_in[5];
    const float* We2  = (const float*)d_in[6];
    const float* be2  = (const float*)d_in[7];
    const float* Wn1  = (const float*)d_in[8];
    const float* bn1  = (const float*)d_in[9];
    const float* Wn2  = (const float*)d_in[10];
    const float* bn2  = (const float*)d_in[11];
    const float* Wc1  = (const float*)d_in[12];
    const float* bc1  = (const float*)d_in[13];
    const float* Wc2  = (const float*)d_in[14];

    float* outh = (float*)d_out;
    float* outx = outh + (size_t)NH;
    float* ws   = (float*)d_ws;

    fold_weights<<<322, 128, 0, stream>>>(We2, be2, Wn1, bn1, Wc1, bc1, ws);
    init_out<<<(NH + NX + 255) / 256, 256, 0, stream>>>(h, x, (float*)d_out);

    const int* es = ei;             // src
    const int* ed = ei + NE;        // dst
    const float* edist = dist;

    if (ws_size >= WS_TOTAL_BYTES) {
        int*   cnt   = (int*)d_ws + IOFF_CNT;
        int*   blk   = (int*)d_ws + IOFF_BLK;
        int*   cur   = (int*)d_ws + IOFF_CUR;
        int*   srcs  = (int*)d_ws + IOFF_SRCS;
        int*   dsts  = (int*)d_ws + IOFF_DSTS;
        float* dists = (float*)((int*)d_ws + IOFF_DISTS);

        zero_cnt<<<NCNT / 256, 256, 0, stream>>>(cnt, cur);
        hist_dst<<<NE / 256, 256, 0, stream>>>(ed, cnt);
        scan1<<<NCNT / 256, 256, 0, stream>>>(cnt, blk);
        scan2<<<1, 256, 0, stream>>>(blk);
        scan3<<<NCNT / 256, 256, 0, stream>>>(cnt, blk);
        scatter_edges<<<NE / 256, 256, 0, stream>>>(es, ed, dist, cnt, cur,
                                                    srcs, dsts, dists);
        es = srcs; ed = dsts; edist = dists;
    }

    egnn_edges<<<1024, 256, 0, stream>>>(h, x, es, ed, edist,
                                         We1, be1, Wn2, bn2, Wc2, ws,
                                         outh, outx);
}